// Round 3
// baseline (433.845 us; speedup 1.0000x reference)
//
#include <hip/hip_runtime.h>
#include <stdint.h>

typedef unsigned short bf16;
typedef __attribute__((ext_vector_type(8))) short short8;
typedef __attribute__((ext_vector_type(4))) float f32x4;

#define MFMA16(a, b, c) __builtin_amdgcn_mfma_f32_16x16x32_bf16((a), (b), (c), 0, 0, 0)

__device__ __forceinline__ bf16 f2bf(float f) {
    unsigned u = __float_as_uint(f);
    u += 0x7fffu + ((u >> 16) & 1u);
    return (bf16)(u >> 16);
}
__device__ __forceinline__ float bf2f(bf16 s) { return __uint_as_float(((unsigned)s) << 16); }

__device__ __forceinline__ void gload_lds16(const void* g, void* lds) {
    auto gp = (const __attribute__((address_space(1))) unsigned int*)(uintptr_t)g;
    auto lp = (__attribute__((address_space(3))) unsigned int*)(uintptr_t)lds;
    __builtin_amdgcn_global_load_lds(gp, lp, 16, 0, 0);
}

// ---------------- K0: weight fp32 -> bf16 ----------------
// a_w / ag_w / g_w are emitted in MFMA fragment order:
//   element index ((kk*8+nt)*64 + lane)*8 + e  holds  w[(nt*16+(lane&15))*128 + kk*32 + (lane>>4)*8 + e]
// so K1 waves read B-fragments as coalesced 16B/lane global loads (L2-hot),
// value-identical to the baseline's w_s[(nt*16+lr)*136 + kk*32 + quad*8] LDS read.
// o_w stays in plain [128][128] layout for K4.
__global__ __launch_bounds__(256) void k_wconv(const float* __restrict__ aw,
                                               const float* __restrict__ agw,
                                               const float* __restrict__ gw,
                                               const float* __restrict__ ow,
                                               bf16* __restrict__ wpk,
                                               bf16* __restrict__ owbf) {
    int i = blockIdx.x * 256 + threadIdx.x;  // grid 256 -> 65536
    if (i < 49152) {
        int m = i >> 14, r = i & 16383;
        int kk = r >> 12, rr = r & 4095;
        int nt = rr >> 9, li = rr & 511;
        int lane = li >> 3, e = li & 7;
        int lr = lane & 15, quad = lane >> 4;
        const float* s = (m == 0) ? aw : (m == 1) ? agw : gw;
        wpk[i] = f2bf(s[(nt * 16 + lr) * 128 + kk * 32 + quad * 8 + e]);
    } else {
        int k = i - 49152;
        owbf[k] = f2bf(ow[k]);
    }
}

// ---------------- K1: LN(z) + 3 projections, write a_t (transposed) + gate ----------------
// Baseline data paths (136-stride zn_s, scalar epilogue stores) with the weight
// LDS staging deleted: B-fragments come straight from global (L2) in fragment
// order. 5 barriers instead of ~11; LDS 34 KB instead of 53 KB.
__global__ __launch_bounds__(256) void k_ln_proj(const float* __restrict__ z,
                                                 const float* __restrict__ ng,
                                                 const float* __restrict__ nb,
                                                 const float* __restrict__ ab,
                                                 const float* __restrict__ agb,
                                                 const float* __restrict__ gbv,
                                                 const bf16* __restrict__ wpk,
                                                 bf16* __restrict__ a_t,
                                                 bf16* __restrict__ gbuf) {
    __shared__ bf16 zn_s[64 * 136];    // padded rows (272 B stride, 16B aligned) — baseline layout
    __shared__ bf16 st[8192];          // epilogue staging: a as [c][64], g as [64][128] — baseline layout
    __shared__ float ng_s[128], nb_s[128];

    const int t = threadIdx.x;
    const int r0 = blockIdx.x * 64;

    if (t < 128) { ng_s[t] = ng[t]; nb_s[t] = nb[t]; }

    // ---- LayerNorm over z_dim=128, 4 lanes per row (baseline-identical) ----
    {
        int row = t >> 2, q = t & 3;
        const float* zp = z + (size_t)(r0 + row) * 128 + q * 32;
        float x[32];
        float s = 0.f, ss = 0.f;
#pragma unroll
        for (int i = 0; i < 8; ++i) {
            float4 v = ((const float4*)zp)[i];
            x[4 * i + 0] = v.x; x[4 * i + 1] = v.y; x[4 * i + 2] = v.z; x[4 * i + 3] = v.w;
        }
#pragma unroll
        for (int i = 0; i < 32; ++i) { s += x[i]; ss += x[i] * x[i]; }
        s += __shfl_xor(s, 1); ss += __shfl_xor(ss, 1);
        s += __shfl_xor(s, 2); ss += __shfl_xor(ss, 2);
        float mean = s * (1.f / 128.f);
        float var = ss * (1.f / 128.f) - mean * mean;
        float rstd = rsqrtf(var + 1e-5f);
        __syncthreads();  // ng_s/nb_s ready
#pragma unroll
        for (int i = 0; i < 32; ++i) {
            int c = q * 32 + i;
            zn_s[row * 136 + c] = f2bf((x[i] - mean) * rstd * ng_s[c] + nb_s[c]);
        }
    }
    __syncthreads();  // zn_s ready

    const int lane = t & 63, w = t >> 6;
    const int lr = lane & 15, quad = lane >> 4;
    const int arow = w * 16 + lr;

    const short8* w0 = (const short8*)wpk + lane;
    const short8* w1 = (const short8*)(wpk + 16384) + lane;
    const short8* w2 = (const short8*)(wpk + 32768) + lane;

    f32x4 zero4 = {0.f, 0.f, 0.f, 0.f};
    f32x4 acc_a[8], acc_b[8];
#pragma unroll
    for (int nt = 0; nt < 8; ++nt) { acc_a[nt] = zero4; acc_b[nt] = zero4; }

    // proj_a + proj_ag fused: af fragment reused for 16 MFMAs; B from global
#pragma unroll
    for (int kk = 0; kk < 4; ++kk) {
        short8 af = *(const short8*)&zn_s[arow * 136 + kk * 32 + quad * 8];
#pragma unroll
        for (int nt = 0; nt < 8; ++nt) {
            acc_a[nt] = MFMA16(af, w0[(kk * 8 + nt) * 64], acc_a[nt]);
            acc_b[nt] = MFMA16(af, w1[(kk * 8 + nt) * 64], acc_b[nt]);
        }
    }

    // a_gated -> st laid out [c][row] (baseline scalar stores)
#pragma unroll
    for (int nt = 0; nt < 8; ++nt) {
        int c = nt * 16 + lr;
        float abv = ab[c], agbv = agb[c];
#pragma unroll
        for (int r = 0; r < 4; ++r) {
            int row = w * 16 + quad * 4 + r;
            float av = acc_a[nt][r] + abv;
            float agvv = acc_b[nt][r] + agbv;
            st[c * 64 + row] = f2bf(av * (1.f / (1.f + __expf(-agvv))));
        }
    }
    __syncthreads();  // st (a) ready

    // coalesced a_t[c][r0..r0+63] store, 16B chunks
#pragma unroll
    for (int i = 0; i < 4; ++i) {
        int idx = t + i * 256;               // 0..1023
        int c = idx >> 3, part = idx & 7;
        *(uint4*)(a_t + (size_t)c * 262144 + r0 + part * 8) = *(const uint4*)&st[c * 64 + part * 8];
    }

    // proj_g (reuse acc_a); reads only zn_s + global weights -> overlaps store above
#pragma unroll
    for (int nt = 0; nt < 8; ++nt) acc_a[nt] = zero4;
#pragma unroll
    for (int kk = 0; kk < 4; ++kk) {
        short8 af = *(const short8*)&zn_s[arow * 136 + kk * 32 + quad * 8];
#pragma unroll
        for (int nt = 0; nt < 8; ++nt)
            acc_a[nt] = MFMA16(af, w2[(kk * 8 + nt) * 64], acc_a[nt]);
    }
    __syncthreads();  // all a_t reads of st done before reuse

    // sigmoid(g) -> st as [row][c] (baseline scalar stores)
#pragma unroll
    for (int nt = 0; nt < 8; ++nt) {
        int c = nt * 16 + lr;
        float gb0 = gbv[c];
#pragma unroll
        for (int r = 0; r < 4; ++r) {
            int row = w * 16 + quad * 4 + r;
            float v = acc_a[nt][r] + gb0;
            st[row * 128 + c] = f2bf(1.f / (1.f + __expf(-v)));
        }
    }
    __syncthreads();  // st (g) ready

#pragma unroll
    for (int i = 0; i < 4; ++i) {
        int idx = t + i * 256;               // 0..1023
        int row = idx >> 4, part = idx & 15;
        *(uint4*)(gbuf + (size_t)(r0 + row) * 128 + part * 8) = *(const uint4*)&st[row * 128 + part * 8];
    }
}

// ---------------- K3: per-channel O_c = A_c A_c^T (bf16 MFMA, swizzled LDS) ----------------
__global__ __launch_bounds__(256) void k_einsum(const bf16* __restrict__ a_t,
                                                bf16* __restrict__ o_t) {
    __shared__ bf16 smem[16384];  // As[0:8192] Bs[8192:16384]; reused as Cs[128][128]
    bf16* As = smem;
    bf16* Bs = smem + 8192;

    const int t = threadIdx.x;
    const int bx = blockIdx.x;
    const int c = bx >> 4;
    const int ti = (bx >> 2) & 3, tj = bx & 3;
    const int i0 = ti * 128, j0 = tj * 128;
    const size_t cbase = (size_t)c * 262144;
    const bf16* Ac = a_t + cbase;

    const int lane = t & 63, w = t >> 6;
    const int lr = lane & 15, quad = lane >> 4;
    const int wi = w >> 1, wj = w & 1;

    f32x4 zero4 = {0.f, 0.f, 0.f, 0.f};
    f32x4 acc[4][4];
#pragma unroll
    for (int mt = 0; mt < 4; ++mt)
#pragma unroll
        for (int nt = 0; nt < 4; ++nt) acc[mt][nt] = zero4;

    for (int kb = 0; kb < 8; ++kb) {
        __syncthreads();  // previous iter's LDS reads done
#pragma unroll
        for (int q = 0; q < 4; ++q) {
            int t16 = (w << 8) + (q << 6) + lane;
            int row = t16 >> 3;
            int cb = t16 & 7;
            int cbg = cb ^ (row & 7);           // XOR swizzle: kill b128 bank conflicts
            int gcol = kb * 64 + cbg * 8;
            gload_lds16(Ac + (size_t)(i0 + row) * 512 + gcol, As + (((w << 8) + (q << 6)) << 3));
            gload_lds16(Ac + (size_t)(j0 + row) * 512 + gcol, Bs + (((w << 8) + (q << 6)) << 3));
        }
        __syncthreads();  // staged (vmcnt drained by barrier)
#pragma unroll
        for (int kk8 = 0; kk8 < 8; kk8 += 4) {
            short8 af[4], bfr[4];
#pragma unroll
            for (int mt = 0; mt < 4; ++mt) {
                int r = wi * 64 + mt * 16 + lr;
                af[mt] = *(const short8*)&As[r * 64 + (((kk8 + quad) ^ (lr & 7)) << 3)];
            }
#pragma unroll
            for (int nt = 0; nt < 4; ++nt) {
                int r = wj * 64 + nt * 16 + lr;
                bfr[nt] = *(const short8*)&Bs[r * 64 + (((kk8 + quad) ^ (lr & 7)) << 3)];
            }
#pragma unroll
            for (int mt = 0; mt < 4; ++mt)
#pragma unroll
                for (int nt = 0; nt < 4; ++nt)
                    acc[mt][nt] = MFMA16(af[mt], bfr[nt], acc[mt][nt]);
        }
    }

    __syncthreads();
    bf16* Cs = smem;  // [128][128]
#pragma unroll
    for (int mt = 0; mt < 4; ++mt)
#pragma unroll
        for (int nt = 0; nt < 4; ++nt)
#pragma unroll
            for (int r = 0; r < 4; ++r) {
                int il = wi * 64 + mt * 16 + quad * 4 + r;
                int jl = wj * 64 + nt * 16 + lr;
                Cs[il * 128 + jl] = f2bf(acc[mt][nt][r]);
            }
    __syncthreads();
    bf16* Oc = o_t + cbase;
#pragma unroll
    for (int i = 0; i < 8; ++i) {
        int idx = t + (i << 8);              // 0..2047
        int row = idx >> 4, part = idx & 15;
        *(uint4*)(Oc + (size_t)(i0 + row) * 512 + j0 + part * 8) = *(const uint4*)&Cs[row * 128 + part * 8];
    }
}

// ---------------- K4: LN over c + out-projection + gate ----------------
__global__ __launch_bounds__(256) void k_out(const bf16* __restrict__ o_t,
                                             const bf16* __restrict__ gbuf,
                                             const float* __restrict__ og,
                                             const float* __restrict__ ob,
                                             const bf16* __restrict__ owbf,
                                             const float* __restrict__ obias,
                                             float* __restrict__ out) {
    __shared__ bf16 pool[128 * 136];  // ot_s [128c][128p] overlays n_s [128p][136c]
    __shared__ float og_s[128], ob_s[128], obi_s[128];
    bf16* ot_s = pool;
    bf16* n_s = pool;

    const int t = threadIdx.x;
    const int p0 = blockIdx.x * 128;
    if (t < 128) { og_s[t] = og[t]; ob_s[t] = ob[t]; obi_s[t] = obias[t]; }

#pragma unroll
    for (int i = 0; i < 8; ++i) {
        int idx = t + (i << 8);
        int c = idx >> 4, part = idx & 15;
        *(uint4*)&ot_s[c * 128 + part * 8] = *(const uint4*)(o_t + (size_t)c * 262144 + p0 + part * 8);
    }
    __syncthreads();

    // LN over c per column; 2 lanes per column
    {
        int col = t >> 1, h = t & 1;
        float s = 0.f, ss = 0.f;
        float xv[64];
#pragma unroll
        for (int k = 0; k < 64; ++k) {
            float x = bf2f(ot_s[(h * 64 + k) * 128 + col]);
            xv[k] = x; s += x; ss += x * x;
        }
        s += __shfl_xor(s, 1); ss += __shfl_xor(ss, 1);
        float mean = s * (1.f / 128.f);
        float var = ss * (1.f / 128.f) - mean * mean;
        float rstd = rsqrtf(var + 1e-5f);
        __syncthreads();  // all ot_s reads complete before overlay write
#pragma unroll
        for (int k = 0; k < 64; ++k) {
            int cc = h * 64 + k;
            n_s[col * 136 + cc] = f2bf((xv[k] - mean) * rstd * og_s[cc] + ob_s[cc]);
        }
    }
    __syncthreads();

    const int lane = t & 63, w = t >> 6;
    const int lr = lane & 15, quad = lane >> 4;
    f32x4 zero4 = {0.f, 0.f, 0.f, 0.f};
    f32x4 acc[2][8];
#pragma unroll
    for (int mt = 0; mt < 2; ++mt)
#pragma unroll
        for (int nt = 0; nt < 8; ++nt) acc[mt][nt] = zero4;

#pragma unroll
    for (int kk = 0; kk < 4; ++kk) {
        short8 af[2];
#pragma unroll
        for (int mt = 0; mt < 2; ++mt)
            af[mt] = *(const short8*)&n_s[(w * 32 + mt * 16 + lr) * 136 + kk * 32 + quad * 8];
#pragma unroll
        for (int nt = 0; nt < 8; ++nt) {
            short8 bfr = *(const short8*)(owbf + (nt * 16 + lr) * 128 + kk * 32 + quad * 8);
            acc[0][nt] = MFMA16(af[0], bfr, acc[0][nt]);
            acc[1][nt] = MFMA16(af[1], bfr, acc[1][nt]);
        }
    }

#pragma unroll
    for (int mt = 0; mt < 2; ++mt)
#pragma unroll
        for (int nt = 0; nt < 8; ++nt) {
            int zd = nt * 16 + lr;
            float bias = obi_s[zd];
#pragma unroll
            for (int r = 0; r < 4; ++r) {
                int m = w * 32 + mt * 16 + quad * 4 + r;
                size_t off = (size_t)(p0 + m) * 128 + zd;
                out[off] = (acc[mt][nt][r] + bias) * bf2f(gbuf[off]);
            }
        }
}

extern "C" void kernel_launch(void* const* d_in, const int* in_sizes, int n_in,
                              void* d_out, int out_size, void* d_ws, size_t ws_size,
                              hipStream_t stream) {
    (void)in_sizes; (void)n_in; (void)out_size; (void)ws_size;
    const float* z   = (const float*)d_in[0];
    const float* ng  = (const float*)d_in[1];
    const float* nb  = (const float*)d_in[2];
    const float* aw  = (const float*)d_in[3];
    const float* ab  = (const float*)d_in[4];
    const float* agw = (const float*)d_in[5];
    const float* agb = (const float*)d_in[6];
    const float* ong = (const float*)d_in[7];
    const float* onb = (const float*)d_in[8];
    const float* ow  = (const float*)d_in[9];
    const float* obi = (const float*)d_in[10];
    const float* gw  = (const float*)d_in[11];
    const float* gbb = (const float*)d_in[12];

    char* ws = (char*)d_ws;
    bf16* wpk  = (bf16*)(ws);                          // 3*16384 bf16 = 98304 B (fragment order)
    bf16* owbf = (bf16*)(ws + 98304);                  // 32768 B
    bf16* a_t  = (bf16*)(ws + 131072);                 // 128*262144*2 = 64 MiB
    bf16* gbuf = (bf16*)(ws + 131072 + 67108864);      // 64 MiB
    bf16* o_t  = (bf16*)(ws + 131072 + 2 * 67108864);  // 64 MiB

    k_wconv<<<256, 256, 0, stream>>>(aw, agw, gw, ow, wpk, owbf);
    k_ln_proj<<<4096, 256, 0, stream>>>(z, ng, nb, ab, agb, gbb, wpk, a_t, gbuf);
    k_einsum<<<2048, 256, 0, stream>>>(a_t, o_t);
    k_out<<<2048, 256, 0, stream>>>(o_t, gbuf, ong, onb, owbf, obi, (float*)d_out);
}

// Round 4
// 429.945 us; speedup vs baseline: 1.0091x; 1.0091x over previous
//
#include <hip/hip_runtime.h>
#include <stdint.h>

typedef unsigned short bf16;
typedef __attribute__((ext_vector_type(8))) short short8;
typedef __attribute__((ext_vector_type(4))) unsigned short u16x4;
typedef __attribute__((ext_vector_type(4))) float f32x4;

#define MFMA16(a, b, c) __builtin_amdgcn_mfma_f32_16x16x32_bf16((a), (b), (c), 0, 0, 0)

__device__ __forceinline__ bf16 f2bf(float f) {
    unsigned u = __float_as_uint(f);
    u += 0x7fffu + ((u >> 16) & 1u);
    return (bf16)(u >> 16);
}
__device__ __forceinline__ float bf2f(bf16 s) { return __uint_as_float(((unsigned)s) << 16); }

__device__ __forceinline__ void gload_lds16(const void* g, void* lds) {
    auto gp = (const __attribute__((address_space(1))) unsigned int*)(uintptr_t)g;
    auto lp = (__attribute__((address_space(3))) unsigned int*)(uintptr_t)lds;
    __builtin_amdgcn_global_load_lds(gp, lp, 16, 0, 0);
}

// ---------------- K0: weight fp32 -> bf16 ----------------
// a_w / ag_w / g_w emitted in MFMA fragment order:
//   element ((kk*8+nt)*64 + lane)*8 + e  holds  w[(nt*16+(lane&15))*128 + kk*32 + (lane>>4)*8 + e]
// K1 stages these LINEARLY into LDS (global_load_lds-compatible) and reads
// B-fragments conflict-free. o_w stays plain [128][128] for K4.
__global__ __launch_bounds__(256) void k_wconv(const float* __restrict__ aw,
                                               const float* __restrict__ agw,
                                               const float* __restrict__ gw,
                                               const float* __restrict__ ow,
                                               bf16* __restrict__ wpk,
                                               bf16* __restrict__ owbf) {
    int i = blockIdx.x * 256 + threadIdx.x;  // grid 256 -> 65536
    if (i < 49152) {
        int m = i >> 14, r = i & 16383;
        int kk = r >> 12, rr = r & 4095;
        int nt = rr >> 9, li = rr & 511;
        int lane = li >> 3, e = li & 7;
        int lr = lane & 15, quad = lane >> 4;
        const float* s = (m == 0) ? aw : (m == 1) ? agw : gw;
        wpk[i] = f2bf(s[(nt * 16 + lr) * 128 + kk * 32 + quad * 8 + e]);
    } else {
        int k = i - 49152;
        owbf[k] = f2bf(ow[k]);
    }
}

// ---------------- K1: LN(z) + 3 projections, write a_t (transposed) + gate ----------------
// Weights staged to LDS fragment-linearly via global_load_lds (cheap staging,
// conflict-free b128 B-reads). All 3 GEMMs run back-to-back (3 acc sets), then
// both epilogues overlay dead LDS: a -> w_s region (stride-72, packed 8B stores),
// g -> zn_s region (stride-136). 8 barriers; w0 staging hidden under LN math.
__global__ __launch_bounds__(256) void k_ln_proj(const float* __restrict__ z,
                                                 const float* __restrict__ ng,
                                                 const float* __restrict__ nb,
                                                 const float* __restrict__ ab,
                                                 const float* __restrict__ agb,
                                                 const float* __restrict__ gbv,
                                                 const bf16* __restrict__ wpk,
                                                 bf16* __restrict__ a_t,
                                                 bf16* __restrict__ gbuf) {
    __shared__ bf16 zn_s[64 * 136];   // LN output (padded rows); g-epilogue staging overlays
    __shared__ bf16 w_s[16384];       // fragment-linear weight; a-epilogue staging overlays
    __shared__ float ng_s[128], nb_s[128];

    const int t = threadIdx.x;
    const int r0 = blockIdx.x * 64;

    auto stage_w = [&](int mat) {
#pragma unroll
        for (int i = 0; i < 8; ++i) {
            int idx = t + i * 256;                 // 0..2047 granules of 8 elems
            gload_lds16(wpk + mat * 16384 + idx * 8, w_s + idx * 8);
        }
    };

    if (t < 128) { ng_s[t] = ng[t]; nb_s[t] = nb[t]; }

    // ---- LayerNorm over z_dim=128, 4 lanes per row ----
    {
        int row = t >> 2, q = t & 3;
        const float* zp = z + (size_t)(r0 + row) * 128 + q * 32;
        float x[32];
#pragma unroll
        for (int i = 0; i < 8; ++i) {
            float4 v = ((const float4*)zp)[i];
            x[4 * i + 0] = v.x; x[4 * i + 1] = v.y; x[4 * i + 2] = v.z; x[4 * i + 3] = v.w;
        }
        stage_w(0);  // async global->LDS; latency hidden under LN math below
        float s = 0.f, ss = 0.f;
#pragma unroll
        for (int i = 0; i < 32; ++i) { s += x[i]; ss += x[i] * x[i]; }
        s += __shfl_xor(s, 1); ss += __shfl_xor(ss, 1);
        s += __shfl_xor(s, 2); ss += __shfl_xor(ss, 2);
        float mean = s * (1.f / 128.f);
        float var = ss * (1.f / 128.f) - mean * mean;
        float rstd = rsqrtf(var + 1e-5f);
        __syncthreads();  // ng_s/nb_s ready (also drains w0 staging)
#pragma unroll
        for (int i = 0; i < 32; ++i) {
            int c = q * 32 + i;
            zn_s[row * 136 + c] = f2bf((x[i] - mean) * rstd * ng_s[c] + nb_s[c]);
        }
    }
    __syncthreads();  // B1: zn_s ready, w0 staged

    const int lane = t & 63, w = t >> 6;
    const int lr = lane & 15, quad = lane >> 4;
    const int arow = w * 16 + lr;

    auto gemmv = [&](f32x4* acc) {
        const short8* ws8 = (const short8*)w_s;
#pragma unroll
        for (int kk = 0; kk < 4; ++kk) {
            short8 af = *(const short8*)&zn_s[arow * 136 + kk * 32 + quad * 8];
#pragma unroll
            for (int nt = 0; nt < 8; ++nt)
                acc[nt] = MFMA16(af, ws8[(kk * 8 + nt) * 64 + lane], acc[nt]);
        }
    };

    f32x4 zero4 = {0.f, 0.f, 0.f, 0.f};
    f32x4 acc_a[8], acc_b[8], acc_g[8];
#pragma unroll
    for (int nt = 0; nt < 8; ++nt) { acc_a[nt] = zero4; acc_b[nt] = zero4; acc_g[nt] = zero4; }

    gemmv(acc_a);             // proj_a (w0)
    __syncthreads();          // B2: w_s reads done
    stage_w(1);
    __syncthreads();          // B3: w1 staged
    gemmv(acc_b);             // proj_ag
    __syncthreads();          // B4: w_s reads done
    stage_w(2);
    __syncthreads();          // B5: w2 staged
    gemmv(acc_g);             // proj_g
    __syncthreads();          // B6: all zn_s/w_s reads done -> overlays safe

    // ---- epilogues into dead LDS ----
    bf16* st_a = w_s;         // [128][72] (stride 72 elems = 144 B, 16B-aligned reads)
    bf16* st_g = zn_s;        // [64][136]

    {   // a_gated: thread owns rows row0..row0+3 of column c -> one packed 8B store
        const int row0 = w * 16 + quad * 4;
#pragma unroll
        for (int nt = 0; nt < 8; ++nt) {
            int c = nt * 16 + lr;
            float abv = ab[c], agbv = agb[c];
            u16x4 pk;
#pragma unroll
            for (int r = 0; r < 4; ++r) {
                float av = acc_a[nt][r] + abv;
                float agvv = acc_b[nt][r] + agbv;
                pk[r] = f2bf(av * (1.f / (1.f + __expf(-agvv))));
            }
            *(u16x4*)&st_a[c * 72 + row0] = pk;
        }
    }
    {   // sigmoid(g): [row][c], stride-136 (~conflict-free scalar stores)
#pragma unroll
        for (int nt = 0; nt < 8; ++nt) {
            int c = nt * 16 + lr;
            float gb0 = gbv[c];
#pragma unroll
            for (int r = 0; r < 4; ++r) {
                int row = w * 16 + quad * 4 + r;
                float v = acc_g[nt][r] + gb0;
                st_g[row * 136 + c] = f2bf(1.f / (1.f + __expf(-v)));
            }
        }
    }
    __syncthreads();          // B7: both staging buffers ready

    // coalesced a_t[c][r0..r0+63] store, 16B chunks
#pragma unroll
    for (int i = 0; i < 4; ++i) {
        int idx = t + i * 256;               // 0..1023
        int c = idx >> 3, part = idx & 7;
        *(uint4*)(a_t + (size_t)c * 262144 + r0 + part * 8) = *(const uint4*)&st_a[c * 72 + part * 8];
    }
    // coalesced gbuf[r0+row][c] store, 16B chunks
#pragma unroll
    for (int i = 0; i < 4; ++i) {
        int idx = t + i * 256;               // 0..1023
        int row = idx >> 4, part = idx & 15;
        *(uint4*)(gbuf + (size_t)(r0 + row) * 128 + part * 8) = *(const uint4*)&st_g[row * 136 + part * 8];
    }
}

// ---------------- K3: per-channel O_c = A_c A_c^T (bf16 MFMA, swizzled LDS) ----------------
__global__ __launch_bounds__(256) void k_einsum(const bf16* __restrict__ a_t,
                                                bf16* __restrict__ o_t) {
    __shared__ bf16 smem[16384];  // As[0:8192] Bs[8192:16384]; reused as Cs[128][128]
    bf16* As = smem;
    bf16* Bs = smem + 8192;

    const int t = threadIdx.x;
    const int bx = blockIdx.x;
    const int c = bx >> 4;
    const int ti = (bx >> 2) & 3, tj = bx & 3;
    const int i0 = ti * 128, j0 = tj * 128;
    const size_t cbase = (size_t)c * 262144;
    const bf16* Ac = a_t + cbase;

    const int lane = t & 63, w = t >> 6;
    const int lr = lane & 15, quad = lane >> 4;
    const int wi = w >> 1, wj = w & 1;

    f32x4 zero4 = {0.f, 0.f, 0.f, 0.f};
    f32x4 acc[4][4];
#pragma unroll
    for (int mt = 0; mt < 4; ++mt)
#pragma unroll
        for (int nt = 0; nt < 4; ++nt) acc[mt][nt] = zero4;

    for (int kb = 0; kb < 8; ++kb) {
        __syncthreads();  // previous iter's LDS reads done
#pragma unroll
        for (int q = 0; q < 4; ++q) {
            int t16 = (w << 8) + (q << 6) + lane;
            int row = t16 >> 3;
            int cb = t16 & 7;
            int cbg = cb ^ (row & 7);           // XOR swizzle: kill b128 bank conflicts
            int gcol = kb * 64 + cbg * 8;
            gload_lds16(Ac + (size_t)(i0 + row) * 512 + gcol, As + (((w << 8) + (q << 6)) << 3));
            gload_lds16(Ac + (size_t)(j0 + row) * 512 + gcol, Bs + (((w << 8) + (q << 6)) << 3));
        }
        __syncthreads();  // staged (vmcnt drained by barrier)
#pragma unroll
        for (int kk8 = 0; kk8 < 8; kk8 += 4) {
            short8 af[4], bfr[4];
#pragma unroll
            for (int mt = 0; mt < 4; ++mt) {
                int r = wi * 64 + mt * 16 + lr;
                af[mt] = *(const short8*)&As[r * 64 + (((kk8 + quad) ^ (lr & 7)) << 3)];
            }
#pragma unroll
            for (int nt = 0; nt < 4; ++nt) {
                int r = wj * 64 + nt * 16 + lr;
                bfr[nt] = *(const short8*)&Bs[r * 64 + (((kk8 + quad) ^ (lr & 7)) << 3)];
            }
#pragma unroll
            for (int mt = 0; mt < 4; ++mt)
#pragma unroll
                for (int nt = 0; nt < 4; ++nt)
                    acc[mt][nt] = MFMA16(af[mt], bfr[nt], acc[mt][nt]);
        }
    }

    __syncthreads();
    bf16* Cs = smem;  // [128][128]
#pragma unroll
    for (int mt = 0; mt < 4; ++mt)
#pragma unroll
        for (int nt = 0; nt < 4; ++nt)
#pragma unroll
            for (int r = 0; r < 4; ++r) {
                int il = wi * 64 + mt * 16 + quad * 4 + r;
                int jl = wj * 64 + nt * 16 + lr;
                Cs[il * 128 + jl] = f2bf(acc[mt][nt][r]);
            }
    __syncthreads();
    bf16* Oc = o_t + cbase;
#pragma unroll
    for (int i = 0; i < 8; ++i) {
        int idx = t + (i << 8);              // 0..2047
        int row = idx >> 4, part = idx & 15;
        *(uint4*)(Oc + (size_t)(i0 + row) * 512 + j0 + part * 8) = *(const uint4*)&Cs[row * 128 + part * 8];
    }
}

// ---------------- K4: LN over c + out-projection + gate ----------------
__global__ __launch_bounds__(256) void k_out(const bf16* __restrict__ o_t,
                                             const bf16* __restrict__ gbuf,
                                             const float* __restrict__ og,
                                             const float* __restrict__ ob,
                                             const bf16* __restrict__ owbf,
                                             const float* __restrict__ obias,
                                             float* __restrict__ out) {
    __shared__ bf16 pool[128 * 136];  // ot_s [128c][128p] overlays n_s [128p][136c]
    __shared__ float og_s[128], ob_s[128], obi_s[128];
    bf16* ot_s = pool;
    bf16* n_s = pool;

    const int t = threadIdx.x;
    const int p0 = blockIdx.x * 128;
    if (t < 128) { og_s[t] = og[t]; ob_s[t] = ob[t]; obi_s[t] = obias[t]; }

#pragma unroll
    for (int i = 0; i < 8; ++i) {
        int idx = t + (i << 8);
        int c = idx >> 4, part = idx & 15;
        *(uint4*)&ot_s[c * 128 + part * 8] = *(const uint4*)(o_t + (size_t)c * 262144 + p0 + part * 8);
    }
    __syncthreads();

    // LN over c per column; 2 lanes per column
    {
        int col = t >> 1, h = t & 1;
        float s = 0.f, ss = 0.f;
        float xv[64];
#pragma unroll
        for (int k = 0; k < 64; ++k) {
            float x = bf2f(ot_s[(h * 64 + k) * 128 + col]);
            xv[k] = x; s += x; ss += x * x;
        }
        s += __shfl_xor(s, 1); ss += __shfl_xor(ss, 1);
        float mean = s * (1.f / 128.f);
        float var = ss * (1.f / 128.f) - mean * mean;
        float rstd = rsqrtf(var + 1e-5f);
        __syncthreads();  // all ot_s reads complete before overlay write
#pragma unroll
        for (int k = 0; k < 64; ++k) {
            int cc = h * 64 + k;
            n_s[col * 136 + cc] = f2bf((xv[k] - mean) * rstd * og_s[cc] + ob_s[cc]);
        }
    }
    __syncthreads();

    const int lane = t & 63, w = t >> 6;
    const int lr = lane & 15, quad = lane >> 4;
    f32x4 zero4 = {0.f, 0.f, 0.f, 0.f};
    f32x4 acc[2][8];
#pragma unroll
    for (int mt = 0; mt < 2; ++mt)
#pragma unroll
        for (int nt = 0; nt < 8; ++nt) acc[mt][nt] = zero4;

#pragma unroll
    for (int kk = 0; kk < 4; ++kk) {
        short8 af[2];
#pragma unroll
        for (int mt = 0; mt < 2; ++mt)
            af[mt] = *(const short8*)&n_s[(w * 32 + mt * 16 + lr) * 136 + kk * 32 + quad * 8];
#pragma unroll
        for (int nt = 0; nt < 8; ++nt) {
            short8 bfr = *(const short8*)(owbf + (nt * 16 + lr) * 128 + kk * 32 + quad * 8);
            acc[0][nt] = MFMA16(af[0], bfr, acc[0][nt]);
            acc[1][nt] = MFMA16(af[1], bfr, acc[1][nt]);
        }
    }

#pragma unroll
    for (int mt = 0; mt < 2; ++mt)
#pragma unroll
        for (int nt = 0; nt < 8; ++nt) {
            int zd = nt * 16 + lr;
            float bias = obi_s[zd];
#pragma unroll
            for (int r = 0; r < 4; ++r) {
                int m = w * 32 + mt * 16 + quad * 4 + r;
                size_t off = (size_t)(p0 + m) * 128 + zd;
                out[off] = (acc[mt][nt][r] + bias) * bf2f(gbuf[off]);
            }
        }
}

extern "C" void kernel_launch(void* const* d_in, const int* in_sizes, int n_in,
                              void* d_out, int out_size, void* d_ws, size_t ws_size,
                              hipStream_t stream) {
    (void)in_sizes; (void)n_in; (void)out_size; (void)ws_size;
    const float* z   = (const float*)d_in[0];
    const float* ng  = (const float*)d_in[1];
    const float* nb  = (const float*)d_in[2];
    const float* aw  = (const float*)d_in[3];
    const float* ab  = (const float*)d_in[4];
    const float* agw = (const float*)d_in[5];
    const float* agb = (const float*)d_in[6];
    const float* ong = (const float*)d_in[7];
    const float* onb = (const float*)d_in[8];
    const float* ow  = (const float*)d_in[9];
    const float* obi = (const float*)d_in[10];
    const float* gw  = (const float*)d_in[11];
    const float* gbb = (const float*)d_in[12];

    char* ws = (char*)d_ws;
    bf16* wpk  = (bf16*)(ws);                          // 3*16384 bf16 = 98304 B (fragment order)
    bf16* owbf = (bf16*)(ws + 98304);                  // 32768 B
    bf16* a_t  = (bf16*)(ws + 131072);                 // 128*262144*2 = 64 MiB
    bf16* gbuf = (bf16*)(ws + 131072 + 67108864);      // 64 MiB
    bf16* o_t  = (bf16*)(ws + 131072 + 2 * 67108864);  // 64 MiB

    k_wconv<<<256, 256, 0, stream>>>(aw, agw, gw, ow, wpk, owbf);
    k_ln_proj<<<4096, 256, 0, stream>>>(z, ng, nb, ab, agb, gbb, wpk, a_t, gbuf);
    k_einsum<<<2048, 256, 0, stream>>>(a_t, o_t);
    k_out<<<2048, 256, 0, stream>>>(o_t, gbuf, ong, onb, owbf, obi, (float*)d_out);
}

// Round 7
// 413.350 us; speedup vs baseline: 1.0496x; 1.0401x over previous
//
#include <hip/hip_runtime.h>
#include <stdint.h>

typedef unsigned short bf16;
typedef __attribute__((ext_vector_type(8))) short short8;
typedef __attribute__((ext_vector_type(4))) float f32x4;

#define MFMA16(a, b, c) __builtin_amdgcn_mfma_f32_16x16x32_bf16((a), (b), (c), 0, 0, 0)

__device__ __forceinline__ bf16 f2bf(float f) {
    unsigned u = __float_as_uint(f);
    u += 0x7fffu + ((u >> 16) & 1u);
    return (bf16)(u >> 16);
}
__device__ __forceinline__ float bf2f(bf16 s) { return __uint_as_float(((unsigned)s) << 16); }

__device__ __forceinline__ void gload_lds16(const void* g, void* lds) {
    auto gp = (const __attribute__((address_space(1))) unsigned int*)(uintptr_t)g;
    auto lp = (__attribute__((address_space(3))) unsigned int*)(uintptr_t)lds;
    __builtin_amdgcn_global_load_lds(gp, lp, 16, 0, 0);
}

// ---------------- K0: weight fp32 -> bf16 ----------------
__global__ __launch_bounds__(256) void k_wconv(const float* __restrict__ aw,
                                               const float* __restrict__ agw,
                                               const float* __restrict__ gw,
                                               const float* __restrict__ ow,
                                               bf16* __restrict__ wbf,
                                               bf16* __restrict__ owbf) {
    int i = blockIdx.x * 256 + threadIdx.x;  // grid 256 -> 65536
    int m = i >> 14, k = i & 16383;
    const float* s = (m == 0) ? aw : (m == 1) ? agw : (m == 2) ? gw : ow;
    float v = s[k];
    if (m < 3) wbf[i] = f2bf(v); else owbf[k] = f2bf(v);
}

// ---------------- K1: LN(z) + 3 projections, write a_t (transposed) + gate ----------------
__global__ __launch_bounds__(256) void k_ln_proj(const float* __restrict__ z,
                                                 const float* __restrict__ ng,
                                                 const float* __restrict__ nb,
                                                 const float* __restrict__ ab,
                                                 const float* __restrict__ agb,
                                                 const float* __restrict__ gbv,
                                                 const bf16* __restrict__ wbf,
                                                 bf16* __restrict__ a_t,
                                                 bf16* __restrict__ gbuf) {
    __shared__ bf16 zn_s[64 * 136];    // padded rows (272 B stride, 16B aligned)
    __shared__ bf16 w_s[128 * 136];    // current weight matrix, padded; first 8192 reused as store-stage
    __shared__ float ng_s[128], nb_s[128];

    const int t = threadIdx.x;
    const int r0 = blockIdx.x * 64;
    bf16* st = w_s;  // 8192-element staging overlay (guarded by barriers)

    if (t < 128) { ng_s[t] = ng[t]; nb_s[t] = nb[t]; }

    // ---- LayerNorm over z_dim=128, 4 lanes per row ----
    {
        int row = t >> 2, q = t & 3;
        const float* zp = z + (size_t)(r0 + row) * 128 + q * 32;
        float x[32];
        float s = 0.f, ss = 0.f;
#pragma unroll
        for (int i = 0; i < 8; ++i) {
            float4 v = ((const float4*)zp)[i];
            x[4 * i + 0] = v.x; x[4 * i + 1] = v.y; x[4 * i + 2] = v.z; x[4 * i + 3] = v.w;
        }
#pragma unroll
        for (int i = 0; i < 32; ++i) { s += x[i]; ss += x[i] * x[i]; }
        s += __shfl_xor(s, 1); ss += __shfl_xor(ss, 1);
        s += __shfl_xor(s, 2); ss += __shfl_xor(ss, 2);
        float mean = s * (1.f / 128.f);
        float var = ss * (1.f / 128.f) - mean * mean;
        float rstd = rsqrtf(var + 1e-5f);
        __syncthreads();  // ng_s/nb_s ready
#pragma unroll
        for (int i = 0; i < 32; ++i) {
            int c = q * 32 + i;
            zn_s[row * 136 + c] = f2bf((x[i] - mean) * rstd * ng_s[c] + nb_s[c]);
        }
    }

    const int lane = t & 63, w = t >> 6;
    const int lr = lane & 15, quad = lane >> 4;
    const int arow = w * 16 + lr;

    auto stage_w = [&](int mat) {
        const uint4* src = (const uint4*)(wbf + mat * 16384);
#pragma unroll
        for (int i = 0; i < 8; ++i) {
            int idx = t + i * 256;            // 0..2047
            int row = idx >> 4, part = idx & 15;
            *(uint4*)&w_s[row * 136 + part * 8] = src[idx];
        }
    };
    auto gemmv = [&](f32x4* acc) {
#pragma unroll
        for (int kk = 0; kk < 4; ++kk) {
            short8 af = *(const short8*)&zn_s[arow * 136 + kk * 32 + quad * 8];
#pragma unroll
            for (int nt = 0; nt < 8; ++nt) {
                short8 bfr = *(const short8*)&w_s[(nt * 16 + lr) * 136 + kk * 32 + quad * 8];
                acc[nt] = MFMA16(af, bfr, acc[nt]);
            }
        }
    };

    f32x4 zero4 = {0.f, 0.f, 0.f, 0.f};
    f32x4 acc_a[8], acc_b[8];
#pragma unroll
    for (int nt = 0; nt < 8; ++nt) { acc_a[nt] = zero4; acc_b[nt] = zero4; }

    stage_w(0);
    __syncthreads();          // zn_s + a_w staged
    gemmv(acc_a);             // proj_a
    __syncthreads();
    stage_w(1);
    __syncthreads();
    gemmv(acc_b);             // proj_ag
    __syncthreads();          // all reads of w_s done before reusing as st

    // a_gated -> st laid out [c][row] for transposed write
#pragma unroll
    for (int nt = 0; nt < 8; ++nt) {
        int c = nt * 16 + lr;
        float abv = ab[c], agbv = agb[c];
#pragma unroll
        for (int r = 0; r < 4; ++r) {
            int row = w * 16 + quad * 4 + r;
            float av = acc_a[nt][r] + abv;
            float agvv = acc_b[nt][r] + agbv;
            st[c * 64 + row] = f2bf(av * (1.f / (1.f + __expf(-agvv))));
        }
    }
    __syncthreads();
    // write a_t[c][r0..r0+63], 16B chunks
#pragma unroll
    for (int i = 0; i < 4; ++i) {
        int idx = t + i * 256;               // 0..1023
        int c = idx >> 3, part = idx & 7;
        *(uint4*)(a_t + (size_t)c * 262144 + r0 + part * 8) = *(const uint4*)&st[c * 64 + part * 8];
    }
    __syncthreads();

    stage_w(2);
    __syncthreads();
#pragma unroll
    for (int nt = 0; nt < 8; ++nt) acc_a[nt] = zero4;
    gemmv(acc_a);             // proj_g
    __syncthreads();          // w_s reads done before reuse as st
#pragma unroll
    for (int nt = 0; nt < 8; ++nt) {
        int c = nt * 16 + lr;
        float gb0 = gbv[c];
#pragma unroll
        for (int r = 0; r < 4; ++r) {
            int row = w * 16 + quad * 4 + r;
            float v = acc_a[nt][r] + gb0;
            st[row * 128 + c] = f2bf(1.f / (1.f + __expf(-v)));
        }
    }
    __syncthreads();
#pragma unroll
    for (int i = 0; i < 4; ++i) {
        int idx = t + i * 256;               // 0..1023
        int row = idx >> 4, part = idx & 15;
        *(uint4*)(gbuf + (size_t)(r0 + row) * 128 + part * 8) = *(const uint4*)&st[row * 128 + part * 8];
    }
}

// ---------------- K3: per-channel O_c = A_c A_c^T (bf16 MFMA, swizzled LDS) ----------------
// ONLY change vs the proven 423us baseline: bijective XCD blockIdx swizzle
// (2048 % 8 == 0). Blocks are independent; a pure index permutation cannot
// change values — it only co-locates the 16 tiles of one channel on one XCD L2.
__global__ __launch_bounds__(256) void k_einsum(const bf16* __restrict__ a_t,
                                                bf16* __restrict__ o_t) {
    __shared__ bf16 smem[16384];  // As[0:8192] Bs[8192:16384]; reused as Cs[128][128]
    bf16* As = smem;
    bf16* Bs = smem + 8192;

    const int t = threadIdx.x;
    const int bx = ((blockIdx.x & 7) << 8) + (blockIdx.x >> 3);  // XCD swizzle (bijective)
    const int c = bx >> 4;
    const int ti = (bx >> 2) & 3, tj = bx & 3;
    const int i0 = ti * 128, j0 = tj * 128;
    const size_t cbase = (size_t)c * 262144;
    const bf16* Ac = a_t + cbase;

    const int lane = t & 63, w = t >> 6;
    const int lr = lane & 15, quad = lane >> 4;
    const int wi = w >> 1, wj = w & 1;

    f32x4 zero4 = {0.f, 0.f, 0.f, 0.f};
    f32x4 acc[4][4];
#pragma unroll
    for (int mt = 0; mt < 4; ++mt)
#pragma unroll
        for (int nt = 0; nt < 4; ++nt) acc[mt][nt] = zero4;

    for (int kb = 0; kb < 8; ++kb) {
        __syncthreads();  // previous iter's LDS reads done
#pragma unroll
        for (int q = 0; q < 4; ++q) {
            int t16 = (w << 8) + (q << 6) + lane;
            int row = t16 >> 3;
            int cb = t16 & 7;
            int cbg = cb ^ (row & 7);           // XOR swizzle: kill b128 bank conflicts
            int gcol = kb * 64 + cbg * 8;
            gload_lds16(Ac + (size_t)(i0 + row) * 512 + gcol, As + (((w << 8) + (q << 6)) << 3));
            gload_lds16(Ac + (size_t)(j0 + row) * 512 + gcol, Bs + (((w << 8) + (q << 6)) << 3));
        }
        __syncthreads();  // staged (vmcnt drained by barrier)
#pragma unroll
        for (int kk8 = 0; kk8 < 8; kk8 += 4) {
            short8 af[4], bfr[4];
#pragma unroll
            for (int mt = 0; mt < 4; ++mt) {
                int r = wi * 64 + mt * 16 + lr;
                af[mt] = *(const short8*)&As[r * 64 + (((kk8 + quad) ^ (lr & 7)) << 3)];
            }
#pragma unroll
            for (int nt = 0; nt < 4; ++nt) {
                int r = wj * 64 + nt * 16 + lr;
                bfr[nt] = *(const short8*)&Bs[r * 64 + (((kk8 + quad) ^ (lr & 7)) << 3)];
            }
#pragma unroll
            for (int mt = 0; mt < 4; ++mt)
#pragma unroll
                for (int nt = 0; nt < 4; ++nt)
                    acc[mt][nt] = MFMA16(af[mt], bfr[nt], acc[mt][nt]);
        }
    }

    __syncthreads();
    bf16* Cs = smem;  // [128][128]
#pragma unroll
    for (int mt = 0; mt < 4; ++mt)
#pragma unroll
        for (int nt = 0; nt < 4; ++nt)
#pragma unroll
            for (int r = 0; r < 4; ++r) {
                int il = wi * 64 + mt * 16 + quad * 4 + r;
                int jl = wj * 64 + nt * 16 + lr;
                Cs[il * 128 + jl] = f2bf(acc[mt][nt][r]);
            }
    __syncthreads();
    bf16* Oc = o_t + cbase;
#pragma unroll
    for (int i = 0; i < 8; ++i) {
        int idx = t + (i << 8);              // 0..2047
        int row = idx >> 4, part = idx & 15;
        *(uint4*)(Oc + (size_t)(i0 + row) * 512 + j0 + part * 8) = *(const uint4*)&Cs[row * 128 + part * 8];
    }
}

// ---------------- K4: LN over c + out-projection + gate ----------------
__global__ __launch_bounds__(256) void k_out(const bf16* __restrict__ o_t,
                                             const bf16* __restrict__ gbuf,
                                             const float* __restrict__ og,
                                             const float* __restrict__ ob,
                                             const bf16* __restrict__ owbf,
                                             const float* __restrict__ obias,
                                             float* __restrict__ out) {
    __shared__ bf16 pool[128 * 136];  // ot_s [128c][128p] overlays n_s [128p][136c]
    __shared__ float og_s[128], ob_s[128], obi_s[128];
    bf16* ot_s = pool;
    bf16* n_s = pool;

    const int t = threadIdx.x;
    const int p0 = blockIdx.x * 128;
    if (t < 128) { og_s[t] = og[t]; ob_s[t] = ob[t]; obi_s[t] = obias[t]; }

#pragma unroll
    for (int i = 0; i < 8; ++i) {
        int idx = t + (i << 8);
        int c = idx >> 4, part = idx & 15;
        *(uint4*)&ot_s[c * 128 + part * 8] = *(const uint4*)(o_t + (size_t)c * 262144 + p0 + part * 8);
    }
    __syncthreads();

    // LN over c per column; 2 lanes per column
    {
        int col = t >> 1, h = t & 1;
        float s = 0.f, ss = 0.f;
        float xv[64];
#pragma unroll
        for (int k = 0; k < 64; ++k) {
            float x = bf2f(ot_s[(h * 64 + k) * 128 + col]);
            xv[k] = x; s += x; ss += x * x;
        }
        s += __shfl_xor(s, 1); ss += __shfl_xor(ss, 1);
        float mean = s * (1.f / 128.f);
        float var = ss * (1.f / 128.f) - mean * mean;
        float rstd = rsqrtf(var + 1e-5f);
        __syncthreads();  // all ot_s reads complete before overlay write
#pragma unroll
        for (int k = 0; k < 64; ++k) {
            int cc = h * 64 + k;
            n_s[col * 136 + cc] = f2bf((xv[k] - mean) * rstd * og_s[cc] + ob_s[cc]);
        }
    }
    __syncthreads();

    const int lane = t & 63, w = t >> 6;
    const int lr = lane & 15, quad = lane >> 4;
    f32x4 zero4 = {0.f, 0.f, 0.f, 0.f};
    f32x4 acc[2][8];
#pragma unroll
    for (int mt = 0; mt < 2; ++mt)
#pragma unroll
        for (int nt = 0; nt < 8; ++nt) acc[mt][nt] = zero4;

#pragma unroll
    for (int kk = 0; kk < 4; ++kk) {
        short8 af[2];
#pragma unroll
        for (int mt = 0; mt < 2; ++mt)
            af[mt] = *(const short8*)&n_s[(w * 32 + mt * 16 + lr) * 136 + kk * 32 + quad * 8];
#pragma unroll
        for (int nt = 0; nt < 8; ++nt) {
            short8 bfr = *(const short8*)(owbf + (nt * 16 + lr) * 128 + kk * 32 + quad * 8);
            acc[0][nt] = MFMA16(af[0], bfr, acc[0][nt]);
            acc[1][nt] = MFMA16(af[1], bfr, acc[1][nt]);
        }
    }

#pragma unroll
    for (int mt = 0; mt < 2; ++mt)
#pragma unroll
        for (int nt = 0; nt < 8; ++nt) {
            int zd = nt * 16 + lr;
            float bias = obi_s[zd];
#pragma unroll
            for (int r = 0; r < 4; ++r) {
                int m = w * 32 + mt * 16 + quad * 4 + r;
                size_t off = (size_t)(p0 + m) * 128 + zd;
                out[off] = (acc[mt][nt][r] + bias) * bf2f(gbuf[off]);
            }
        }
}

extern "C" void kernel_launch(void* const* d_in, const int* in_sizes, int n_in,
                              void* d_out, int out_size, void* d_ws, size_t ws_size,
                              hipStream_t stream) {
    (void)in_sizes; (void)n_in; (void)out_size; (void)ws_size;
    const float* z   = (const float*)d_in[0];
    const float* ng  = (const float*)d_in[1];
    const float* nb  = (const float*)d_in[2];
    const float* aw  = (const float*)d_in[3];
    const float* ab  = (const float*)d_in[4];
    const float* agw = (const float*)d_in[5];
    const float* agb = (const float*)d_in[6];
    const float* ong = (const float*)d_in[7];
    const float* onb = (const float*)d_in[8];
    const float* ow  = (const float*)d_in[9];
    const float* obi = (const float*)d_in[10];
    const float* gw  = (const float*)d_in[11];
    const float* gbb = (const float*)d_in[12];

    char* ws = (char*)d_ws;
    bf16* wbf  = (bf16*)(ws);                          // 3*16384 bf16 = 98304 B
    bf16* owbf = (bf16*)(ws + 98304);                  // 32768 B
    bf16* a_t  = (bf16*)(ws + 131072);                 // 128*262144*2 = 64 MiB
    bf16* gbuf = (bf16*)(ws + 131072 + 67108864);      // 64 MiB
    bf16* o_t  = (bf16*)(ws + 131072 + 2 * 67108864);  // 64 MiB

    k_wconv<<<256, 256, 0, stream>>>(aw, agw, gw, ow, wbf, owbf);
    k_ln_proj<<<4096, 256, 0, stream>>>(z, ng, nb, ab, agb, gbb, wbf, a_t, gbuf);
    k_einsum<<<2048, 256, 0, stream>>>(a_t, o_t);
    k_out<<<2048, 256, 0, stream>>>(o_t, gbuf, ong, onb, owbf, obi, (float*)d_out);
}